// Round 1
// baseline (982.324 us; speedup 1.0000x reference)
//
#include <hip/hip_runtime.h>
#include <math.h>

// Problem constants
#define V_ 25
#define C_ 64
#define D_ 64
#define N_ 64
#define T_ 300
#define R_ (N_*T_)      // 19200 rows
#define K_ (V_*C_)      // 1600 features per row
#define BN_EPS 1e-5f

// Workspace layout (float units)
#define WS_M      0      // mask tanh(fm)+1        [1600]
#define WS_SCALE  1600   // BN scale per k         [1600]
#define WS_SHIFT  3200   // BN shift per k         [1600]
#define WS_SUM    4800   // sum_y per (v,d)        [1600]
#define WS_SQ     6400   // sumsq_y per (v,d)      [1600]

__global__ __launch_bounds__(256) void prep_mask_kernel(
    const float* __restrict__ fm, float* __restrict__ ws)
{
    int j = blockIdx.x * 256 + threadIdx.x;
    if (j < K_) ws[WS_M + j] = tanhf(fm[j]) + 1.0f;
}

__global__ __launch_bounds__(256) void prep_scale_kernel(
    const float* __restrict__ gamma, const float* __restrict__ beta,
    const int* __restrict__ s_out, float* __restrict__ ws)
{
    int k = blockIdx.x * 256 + threadIdx.x;
    if (k < K_) {
        int jj = s_out[k];
        float mean = ws[WS_SUM + jj] * (1.0f / (float)R_);
        float var  = fmaf(-mean, mean, ws[WS_SQ + jj] * (1.0f / (float)R_));
        float inv  = rsqrtf(var + BN_EPS);
        float sc   = gamma[k] * inv;
        ws[WS_SCALE + k] = sc;
        ws[WS_SHIFT + k] = beta[k] - mean * sc;
    }
}

// 64-term dot: a_row (LDS, contiguous c) . Wreg (per-lane column of W) + b[d]
__device__ __forceinline__ float dot64(const float* a_row, const float Wreg[64], float breg)
{
    float acc0 = 0.f, acc1 = 0.f, acc2 = 0.f, acc3 = 0.f;
    const float4* ap = (const float4*)a_row;
    #pragma unroll
    for (int q = 0; q < 16; ++q) {
        float4 av = ap[q];
        acc0 = fmaf(av.x, Wreg[4*q+0], acc0);
        acc1 = fmaf(av.y, Wreg[4*q+1], acc1);
        acc2 = fmaf(av.z, Wreg[4*q+2], acc2);
        acc3 = fmaf(av.w, Wreg[4*q+3], acc3);
    }
    return ((acc0 + acc2) + (acc1 + acc3)) + breg;
}

// Stage 1: load 4 rows (n; t0..t0+3) of x0 into LDS in (c', dt*25+v') order (coalesced
//          100-float chunks per c').
// Stage 2a: gather via shift_in + mask into a_lds[dt][v*64+c] (contiguous in c).
__device__ __forceinline__ void stage_load_gather(
    const float4* __restrict__ x0v4, const int* __restrict__ s_in,
    const float* __restrict__ mws, float* xs, float4* xs4, float* a_lds,
    int n, int t0, int tid)
{
    int base4 = n * 120000 + (t0 * 25) / 4;   // t0 multiple of 4 -> aligned
    #pragma unroll
    for (int i = 0; i < 7; ++i) {
        int idx = tid + i * 256;
        if (idx < 1600) {
            int c  = idx / 25;
            int q4 = idx - c * 25;
            xs4[idx] = x0v4[base4 + c * 1875 + q4];
        }
    }
    __syncthreads();
    #pragma unroll
    for (int i = 0; i < 25; ++i) {
        int e  = tid + i * 256;
        int dt = e / 1600;
        int jv = e - dt * 1600;            // v*64 + c
        int jj = s_in[jv];                 // source feature index v'*64 + c'
        float val = xs[(jj & 63) * 100 + dt * 25 + (jj >> 6)] * mws[jv];
        a_lds[e] = val;
    }
    __syncthreads();
}

// Pass 1: statistics. 1200 blocks x 16 rows (4 tiles of 4). Accumulate sum/sumsq of
// y[r,v,d] in registers across 16 rows, one atomicAdd pair per (v,d) at the end.
__global__ __launch_bounds__(256) void pass1_stats(
    const float* __restrict__ x0, const int* __restrict__ s_in,
    const float* __restrict__ Wg, const float* __restrict__ bg,
    float* __restrict__ ws)
{
    __shared__ float4 xs4[1600];
    __shared__ float4 a4[1600];
    float* xs    = (float*)xs4;
    float* a_lds = (float*)a4;

    int tid = threadIdx.x;
    int l = tid & 63;        // lane = d
    int w = tid >> 6;        // wave id

    float Wreg[64];
    #pragma unroll
    for (int c = 0; c < 64; ++c) Wreg[c] = Wg[c * 64 + l];
    float breg = bg[l];

    float sums[7], sqs[7];
    #pragma unroll
    for (int i = 0; i < 7; ++i) { sums[i] = 0.f; sqs[i] = 0.f; }

    int r0 = blockIdx.x * 16;
    for (int tile = 0; tile < 4; ++tile) {
        int rt = r0 + tile * 4;
        int n  = rt / 300;
        int t0 = rt - n * 300;
        // the sync inside stage_load_gather (after stage1) guarantees the previous
        // tile's matmul reads of a_lds are done before stage2a overwrites it
        stage_load_gather((const float4*)x0, s_in, ws + WS_M, xs, xs4, a_lds, n, t0, tid);
        #pragma unroll
        for (int vi = 0; vi < 7; ++vi) {
            int v = w + 4 * vi;
            if (v < 25) {
                #pragma unroll
                for (int dt = 0; dt < 4; ++dt) {
                    float y = dot64(a_lds + dt * 1600 + v * 64, Wreg, breg);
                    sums[vi] += y;
                    sqs[vi]   = fmaf(y, y, sqs[vi]);
                }
            }
        }
        __syncthreads();   // all waves done reading a_lds before next tile reloads
    }

    #pragma unroll
    for (int vi = 0; vi < 7; ++vi) {
        int v = w + 4 * vi;
        if (v < 25) {
            atomicAdd(&ws[WS_SUM + v * 64 + l], sums[vi]);
            atomicAdd(&ws[WS_SQ  + v * 64 + l], sqs[vi]);
        }
    }
}

// Pass 2: recompute y for 4 rows, gather shift_out, BN affine, residual, ReLU,
// write out in (N,D,T,V) layout (per-d contiguous 100-float chunks).
__global__ __launch_bounds__(256) void pass2_out(
    const float* __restrict__ x0, const int* __restrict__ s_in,
    const int* __restrict__ s_out,
    const float* __restrict__ Wg, const float* __restrict__ bg,
    const float* __restrict__ ws, float* __restrict__ out)
{
    __shared__ float4 xs4[1600];
    __shared__ float4 a4[1600];
    float* xs    = (float*)xs4;
    float* a_lds = (float*)a4;

    int tid = threadIdx.x;
    int l = tid & 63;
    int w = tid >> 6;

    float Wreg[64];
    #pragma unroll
    for (int c = 0; c < 64; ++c) Wreg[c] = Wg[c * 64 + l];
    float breg = bg[l];

    int r0 = blockIdx.x * 4;
    int n  = r0 / 300;
    int t0 = r0 - n * 300;

    stage_load_gather((const float4*)x0, s_in, ws + WS_M, xs, xs4, a_lds, n, t0, tid);

    // matmul: wave w handles row dt=w, all v; write y in-place over a_lds
    {
        int dt = w;
        #pragma unroll
        for (int v = 0; v < 25; ++v) {
            float y = dot64(a_lds + dt * 1600 + v * 64, Wreg, breg);
            a_lds[dt * 1600 + v * 64 + l] = y;   // safe: all 64 reads precede the write
        }
    }
    __syncthreads();

    const float* scale = ws + WS_SCALE;
    const float* shift = ws + WS_SHIFT;
    #pragma unroll
    for (int j = 0; j < 16; ++j) {
        int d = w * 16 + j;
        int base = ((n * 64 + d) * 300 + t0) * 25;
        {
            int e   = l;
            int dt5 = e / 25;
            int v   = e - dt5 * 25;
            int k   = v * 64 + d;
            int jj2 = s_out[k];
            float z   = a_lds[dt5 * 1600 + jj2];
            float val = fmaf(z, scale[k], shift[k]) + xs[d * 100 + e];
            out[base + e] = fmaxf(val, 0.f);
        }
        if (l < 36) {
            int e   = l + 64;
            int dt5 = e / 25;
            int v   = e - dt5 * 25;
            int k   = v * 64 + d;
            int jj2 = s_out[k];
            float z   = a_lds[dt5 * 1600 + jj2];
            float val = fmaf(z, scale[k], shift[k]) + xs[d * 100 + e];
            out[base + e] = fmaxf(val, 0.f);
        }
    }
}

extern "C" void kernel_launch(void* const* d_in, const int* in_sizes, int n_in,
                              void* d_out, int out_size, void* d_ws, size_t ws_size,
                              hipStream_t stream)
{
    const float* x0    = (const float*)d_in[0];
    const float* fm    = (const float*)d_in[1];
    const float* W     = (const float*)d_in[2];
    const float* b     = (const float*)d_in[3];
    const float* gamma = (const float*)d_in[4];
    const float* beta  = (const float*)d_in[5];
    const int*   s_in  = (const int*)d_in[6];
    const int*   s_out = (const int*)d_in[7];
    float* out = (float*)d_out;
    float* ws  = (float*)d_ws;

    // stats area must be zeroed every launch (ws is poisoned with 0xAA)
    (void)hipMemsetAsync(ws + WS_SUM, 0, 2 * K_ * sizeof(float), stream);

    prep_mask_kernel<<<7, 256, 0, stream>>>(fm, ws);
    pass1_stats<<<R_ / 16, 256, 0, stream>>>(x0, s_in, W, b, ws);
    prep_scale_kernel<<<7, 256, 0, stream>>>(gamma, beta, s_out, ws);
    pass2_out<<<R_ / 4, 256, 0, stream>>>(x0, s_in, s_out, W, b, ws, out);
}

// Round 2
// 547.318 us; speedup vs baseline: 1.7948x; 1.7948x over previous
//
#include <hip/hip_runtime.h>
#include <math.h>

// Problem constants
#define V_ 25
#define VP_ 28          // v padded to multiple of 4
#define C_ 64
#define D_ 64
#define N_ 64
#define T_ 300
#define R_ (N_*T_)      // 19200 rows
#define K_ (V_*C_)      // 1600
#define BN_EPS 1e-5f

// Workspace layout (4-byte units)
#define WS_MK     0      // tanh(fm)+1            [1600] f32
#define WS_SCALE  1600   // BN scale per k        [1600] f32
#define WS_SHIFT  3200   // BN shift per k        [1600] f32
#define WS_SUM    4800   // sum_y per (v,d)       [1600] f32
#define WS_SQ     6400   // sumsq_y per (v,d)     [1600] f32
#define WS_WBF    8000   // W as bf16             [4096] u16 = 2048 words

// MFMA fragment types (per cdna_hip_programming.md §3, gfx950-verified layouts)
using bf16x8 = __attribute__((ext_vector_type(8))) short;
using f32x4  = __attribute__((ext_vector_type(4))) float;

__device__ __forceinline__ unsigned short f2bf(float f) {
    unsigned u = __float_as_uint(f);
    return (unsigned short)((u + 0x7FFFu + ((u >> 16) & 1u)) >> 16);
}

// ---------- prep: mask table + bf16 W ----------
__global__ __launch_bounds__(256) void prep_tables(
    const float* __restrict__ fm, const float* __restrict__ W,
    float* __restrict__ ws)
{
    int idx = blockIdx.x * 256 + threadIdx.x;   // grid 16 blocks -> 4096
    if (idx < K_) ws[WS_MK + idx] = tanhf(fm[idx]) + 1.0f;
    if (idx < C_ * D_) ((unsigned short*)(ws + WS_WBF))[idx] = f2bf(W[idx]);
}

// ---------- prep: BN scale/shift from accumulated stats ----------
__global__ __launch_bounds__(256) void prep_scale_kernel(
    const float* __restrict__ gamma, const float* __restrict__ beta,
    const int* __restrict__ s_out, float* __restrict__ ws)
{
    int k = blockIdx.x * 256 + threadIdx.x;
    if (k < K_) {
        int jj = s_out[k];
        float mean = ws[WS_SUM + jj] * (1.0f / (float)R_);
        float var  = fmaf(-mean, mean, ws[WS_SQ + jj] * (1.0f / (float)R_));
        float inv  = rsqrtf(var + BN_EPS);
        float sc   = gamma[k] * inv;
        ws[WS_SCALE + k] = sc;
        ws[WS_SHIFT + k] = beta[k] - mean * sc;
    }
}

// Stage one 4-row x-window into LDS: xs[c*101 + dt*25 + v]  (stride 101 kills
// power-of-2 bank collisions; global reads coalesced along v).
__device__ __forceinline__ void stage_xs(
    const float* __restrict__ x0, float* xs, int n, int t0, int tid)
{
    #pragma unroll
    for (int dt = 0; dt < 4; ++dt) {
        const float* src = x0 + ((size_t)(n * 64) * 300 + (t0 + dt)) * 25;
        #pragma unroll
        for (int i = 0; i < 7; ++i) {
            int idx = i * 256 + tid;
            if (idx < 1600) {
                int c = idx / 25;
                int v = idx - c * 25;
                xs[c * 101 + dt * 25 + v] = src[c * 7500 + v];
            }
        }
    }
}

// Build fragment-major bf16 A buffer: element (u'=v*4+dt, c) -> tile t=u'>>4,
// m=u'&15, h=c>>5, q=(c>>3)&3, j=c&7 at a_fm[((t*2+h)*64 + q*16 + m)*8 + j].
// Consumer ds_read_b128 at lane-consecutive 16B slots: conflict-free.
__device__ __forceinline__ void build_afm(
    const float* xs, unsigned int* a_fm32,
    const int* __restrict__ s_in, const float* __restrict__ mk, int tid)
{
    #pragma unroll
    for (int i = 0; i < 14; ++i) {           // 14*256 = 3584 bf16-pairs
        int e2 = i * 256 + tid;
        int cp = e2 / 112;
        int u  = e2 - cp * 112;
        int c  = cp * 2;
        int v  = u >> 2, dt = u & 3, t = u >> 4, m = u & 15;
        int h  = c >> 5, q = (c >> 3) & 3, j = c & 7;
        int kb = (v < V_) ? (v * 64 + c) : c;     // clamp padded v rows
        int jj0 = s_in[kb], jj1 = s_in[kb + 1];
        float m0 = mk[kb], m1 = mk[kb + 1];
        float f0 = xs[(jj0 & 63) * 101 + dt * 25 + (jj0 >> 6)] * m0;
        float f1 = xs[(jj1 & 63) * 101 + dt * 25 + (jj1 >> 6)] * m1;
        a_fm32[((t * 2 + h) * 64 + q * 16 + m) * 4 + (j >> 1)] =
            (unsigned int)f2bf(f0) | ((unsigned int)f2bf(f1) << 16);
    }
}

// ---------- pass 1: BN statistics ----------
__global__ __launch_bounds__(256) void pass1_stats(
    const float* __restrict__ x0, const int* __restrict__ s_in,
    const float* __restrict__ bg, float* __restrict__ ws)
{
    __shared__ __align__(16) char smem[25856 + 14336]; // xs + a_fm
    float* xs = (float*)smem;
    unsigned short* a_fm = (unsigned short*)(smem + 25856);
    unsigned int* a_fm32 = (unsigned int*)a_fm;

    int tid = threadIdx.x;
    int lane = tid & 63, w = tid >> 6;
    int l15 = lane & 15, q = lane >> 4;
    int d = w * 16 + l15;

    // B fragments: W columns for this wave's n-tile (8 VGPRs)
    const unsigned short* Wbf = (const unsigned short*)(ws + WS_WBF);
    bf16x8 bfrag0, bfrag1;
    #pragma unroll
    for (int j = 0; j < 8; ++j) {
        bfrag0[j] = (short)Wbf[(q * 8 + j) * 64 + d];
        bfrag1[j] = (short)Wbf[(32 + q * 8 + j) * 64 + d];
    }
    float breg = bg[d];

    float sums[7], sqs[7];
    #pragma unroll
    for (int t = 0; t < 7; ++t) { sums[t] = 0.f; sqs[t] = 0.f; }

    #pragma unroll
    for (int st = 0; st < 2; ++st) {
        int r0 = blockIdx.x * 8 + st * 4;
        int n  = r0 / 300;
        int t0 = r0 - n * 300;     // r0 % 4 == 0 and 4 | 300 -> n uniform over dt
        stage_xs(x0, xs, n, t0, tid);
        __syncthreads();
        build_afm(xs, a_fm32, s_in, ws + WS_MK, tid);
        __syncthreads();
        const bf16x8* afp = (const bf16x8*)a_fm;
        #pragma unroll
        for (int t = 0; t < 7; ++t) {
            bf16x8 a0 = afp[(t * 2 + 0) * 64 + lane];
            bf16x8 a1 = afp[(t * 2 + 1) * 64 + lane];
            f32x4 acc = {0.f, 0.f, 0.f, 0.f};
            acc = __builtin_amdgcn_mfma_f32_16x16x32_bf16(a0, bfrag0, acc, 0, 0, 0);
            acc = __builtin_amdgcn_mfma_f32_16x16x32_bf16(a1, bfrag1, acc, 0, 0, 0);
            #pragma unroll
            for (int r = 0; r < 4; ++r) {
                float y = acc[r] + breg;
                sums[t] += y;
                sqs[t]   = fmaf(y, y, sqs[t]);
            }
        }
        __syncthreads();   // all waves done with a_fm before next sub-tile rebuild
    }

    #pragma unroll
    for (int t = 0; t < 7; ++t) {
        int v = t * 4 + q;          // C-layout: quad == v within tile
        if (v < V_) {
            atomicAdd(&ws[WS_SUM + v * 64 + d], sums[t]);
            atomicAdd(&ws[WS_SQ  + v * 64 + d], sqs[t]);
        }
    }
}

// ---------- pass 2: recompute y, shift_out, BN affine, residual, ReLU ----------
__global__ __launch_bounds__(256) void pass2_out(
    const float* __restrict__ x0, const int* __restrict__ s_in,
    const int* __restrict__ s_out, const float* __restrict__ bg,
    const float* __restrict__ ws, float* __restrict__ out)
{
    // xs (25856 B) and y_lds (30464 B) are time-disjoint -> union; a_fm after.
    __shared__ __align__(16) char smem[30464 + 14336];
    float* xs    = (float*)smem;
    float* y_lds = (float*)smem;            // [u''=v*4+dt][68] padded
    unsigned short* a_fm = (unsigned short*)(smem + 30464);
    unsigned int* a_fm32 = (unsigned int*)a_fm;

    int tid = threadIdx.x;
    int lane = tid & 63, w = tid >> 6;
    int l15 = lane & 15, q = lane >> 4;
    int d = w * 16 + l15;

    const unsigned short* Wbf = (const unsigned short*)(ws + WS_WBF);
    bf16x8 bfrag0, bfrag1;
    #pragma unroll
    for (int j = 0; j < 8; ++j) {
        bfrag0[j] = (short)Wbf[(q * 8 + j) * 64 + d];
        bfrag1[j] = (short)Wbf[(32 + q * 8 + j) * 64 + d];
    }
    float breg = bg[d];

    int r0 = blockIdx.x * 4;
    int n  = r0 / 300;
    int t0 = r0 - n * 300;

    stage_xs(x0, xs, n, t0, tid);
    __syncthreads();
    build_afm(xs, a_fm32, s_in, ws + WS_MK, tid);
    __syncthreads();                      // xs dead from here; y_lds takes over

    const bf16x8* afp = (const bf16x8*)a_fm;
    #pragma unroll
    for (int t = 0; t < 7; ++t) {
        bf16x8 a0 = afp[(t * 2 + 0) * 64 + lane];
        bf16x8 a1 = afp[(t * 2 + 1) * 64 + lane];
        f32x4 acc = {0.f, 0.f, 0.f, 0.f};
        acc = __builtin_amdgcn_mfma_f32_16x16x32_bf16(a0, bfrag0, acc, 0, 0, 0);
        acc = __builtin_amdgcn_mfma_f32_16x16x32_bf16(a1, bfrag1, acc, 0, 0, 0);
        #pragma unroll
        for (int r = 0; r < 4; ++r)
            y_lds[(t * 16 + q * 4 + r) * 68 + d] = acc[r] + breg;
    }
    __syncthreads();

    const float* sc = ws + WS_SCALE;
    const float* sh = ws + WS_SHIFT;
    #pragma unroll
    for (int i = 0; i < 25; ++i) {        // 25*256 = 6400 outputs
        int e   = i * 256 + tid;
        int dd  = e / 100;
        int rem = e - dd * 100;
        int dt  = rem / 25;
        int v   = rem - dt * 25;
        int k   = v * 64 + dd;
        int jj2 = s_out[k];
        float z = y_lds[((jj2 >> 6) * 4 + dt) * 68 + (jj2 & 63)];
        int ga  = ((n * 64 + dd) * 300 + t0 + dt) * 25 + v;
        float val = fmaf(z, sc[k], sh[k]) + x0[ga];
        out[ga] = fmaxf(val, 0.f);
    }
}

extern "C" void kernel_launch(void* const* d_in, const int* in_sizes, int n_in,
                              void* d_out, int out_size, void* d_ws, size_t ws_size,
                              hipStream_t stream)
{
    const float* x0    = (const float*)d_in[0];
    const float* fm    = (const float*)d_in[1];
    const float* W     = (const float*)d_in[2];
    const float* b     = (const float*)d_in[3];
    const float* gamma = (const float*)d_in[4];
    const float* beta  = (const float*)d_in[5];
    const int*   s_in  = (const int*)d_in[6];
    const int*   s_out = (const int*)d_in[7];
    float* out = (float*)d_out;
    float* ws  = (float*)d_ws;

    (void)hipMemsetAsync(ws + WS_SUM, 0, 2 * K_ * sizeof(float), stream);
    prep_tables<<<16, 256, 0, stream>>>(fm, W, ws);
    pass1_stats<<<R_ / 8, 256, 0, stream>>>(x0, s_in, b, ws);
    prep_scale_kernel<<<7, 256, 0, stream>>>(gamma, beta, s_out, ws);
    pass2_out<<<R_ / 4, 256, 0, stream>>>(x0, s_in, s_out, b, ws, out);
}

// Round 3
// 344.093 us; speedup vs baseline: 2.8548x; 1.5906x over previous
//
#include <hip/hip_runtime.h>
#include <math.h>

// Problem constants
#define V_ 25
#define C_ 64
#define D_ 64
#define N_ 64
#define T_ 300
#define R_ (N_*T_)      // 19200 rows
#define K_ (V_*C_)      // 1600
#define BN_EPS 1e-5f

// Workspace layout (4-byte units)
#define WS_MK     0      // mask tanh(fm)+1, by k=v*64+c           [1600] f32
#define WS_OFF    1600   // gather offset (c'*7500+v'), by k       [1600] i32
#define WS_SCALE  3200   // BN scale, OUTPUT order kk=dd*25+v      [1600] f32
#define WS_SHIFT  4800   // BN shift, OUTPUT order kk              [1600] f32
#define WS_VP     6400   // s_out jj, OUTPUT order kk              [1600] i32
#define WS_SUM    8000   // sum_y per (v,d) flat jj                [1600] f32
#define WS_SQ     9600   // sumsq_y per (v,d) flat jj              [1600] f32
#define WS_WBF    11200  // W as bf16                              [4096] u16

using bf16x8 = __attribute__((ext_vector_type(8))) short;
using f32x4  = __attribute__((ext_vector_type(4))) float;

__device__ __forceinline__ unsigned short f2bf(float f) {
    unsigned u = __float_as_uint(f);
    return (unsigned short)((u + 0x7FFFu + ((u >> 16) & 1u)) >> 16);
}

// ---------- prep: mask+offset tables (k order) + bf16 W ----------
__global__ __launch_bounds__(256) void prep_tables(
    const float* __restrict__ fm, const float* __restrict__ W,
    const int* __restrict__ s_in, float* __restrict__ ws)
{
    int idx = blockIdx.x * 256 + threadIdx.x;   // 16 blocks -> 4096
    if (idx < K_) {
        ws[WS_MK + idx] = tanhf(fm[idx]) + 1.0f;
        int jj = s_in[idx];
        ((int*)ws)[WS_OFF + idx] = (jj & 63) * 7500 + (jj >> 6);
    }
    if (idx < C_ * D_) ((unsigned short*)(ws + WS_WBF))[idx] = f2bf(W[idx]);
}

// ---------- prep: BN scale/shift + shift_out table, OUTPUT order ----------
__global__ __launch_bounds__(256) void prep_scale_kernel(
    const float* __restrict__ gamma, const float* __restrict__ beta,
    const int* __restrict__ s_out, float* __restrict__ ws)
{
    int kk = blockIdx.x * 256 + threadIdx.x;    // kk = dd*25 + v
    if (kk < K_) {
        int dd = kk / 25;
        int v  = kk - dd * 25;
        int k  = v * 64 + dd;
        int jj = s_out[k];
        float mean = ws[WS_SUM + jj] * (1.0f / (float)R_);
        float var  = fmaf(-mean, mean, ws[WS_SQ + jj] * (1.0f / (float)R_));
        float inv  = rsqrtf(var + BN_EPS);
        float sc   = gamma[k] * inv;
        ws[WS_SCALE + kk] = sc;
        ws[WS_SHIFT + kk] = beta[k] - mean * sc;
        ((int*)ws)[WS_VP + kk] = jj;
    }
}

// Build fragment-major bf16 A buffer directly from global x0.
// Work unit = one 32-bit word of a_fm: (T in [0,14), q2 in [0,4), m in [0,16),
// jw in [0,4)). Word address = (T*64 + q2*16 + m)*4 + jw -> bank = (4m+jw)&31.
// Lane -> (m = lane>>2, jw = lane&3) makes bank == lane&31: conflict-free writes.
// Read side (ds_read_b128 at chunk T*64+lane) is the canonical conflict-free
// pattern. A-frag semantics: tile t=T>>1 rows u=t*16+m (v=u>>2,dt=u&3),
// channels c = (T&1)*32 + q2*8 + jw*2 + {0,1}.
__device__ __forceinline__ void build_afm(
    const float* __restrict__ xwin, unsigned int* a_fm32,
    const int* __restrict__ offs, const float* __restrict__ mk,
    int lane, int w)
{
    int m  = lane >> 2;
    int jw = lane & 3;
    int dt = m & 3;
    int vh = m >> 2;            // v = t*4 + vh
    #pragma unroll
    for (int i = 0; i < 14; ++i) {
        int combo = i * 4 + w;          // (T,q2) in [0,56)
        int T  = combo >> 2;
        int q2 = combo & 3;
        int t  = T >> 1;
        int c0 = (T & 1) * 32 + q2 * 8 + jw * 2;
        int v  = t * 4 + vh;
        int kb = (v < V_) ? (v * 64 + c0) : c0;   // clamp padded rows
        int   o0 = offs[kb],   o1 = offs[kb + 1];
        float m0 = mk[kb],     m1 = mk[kb + 1];
        float f0 = xwin[o0 + dt * 25] * m0;
        float f1 = xwin[o1 + dt * 25] * m1;
        a_fm32[(T * 64 + q2 * 16 + m) * 4 + jw] =
            (unsigned int)f2bf(f0) | ((unsigned int)f2bf(f1) << 16);
    }
}

// ---------- pass 1: BN statistics ----------
__global__ __launch_bounds__(256) void pass1_stats(
    const float* __restrict__ x0, const float* __restrict__ bg,
    float* __restrict__ ws)
{
    __shared__ __align__(16) unsigned int a_fm32[3584];   // 14336 B
    const bf16x8* afp = (const bf16x8*)a_fm32;

    int tid = threadIdx.x;
    int lane = tid & 63, w = tid >> 6;
    int l15 = lane & 15, q = lane >> 4;
    int d = w * 16 + l15;

    const unsigned short* Wbf = (const unsigned short*)(ws + WS_WBF);
    bf16x8 bfrag0, bfrag1;
    #pragma unroll
    for (int j = 0; j < 8; ++j) {
        bfrag0[j] = (short)Wbf[(q * 8 + j) * 64 + d];
        bfrag1[j] = (short)Wbf[(32 + q * 8 + j) * 64 + d];
    }
    float breg = bg[d];

    const int*   offs = (const int*)ws + WS_OFF;
    const float* mk   = ws + WS_MK;

    float sums[7], sqs[7];
    #pragma unroll
    for (int t = 0; t < 7; ++t) { sums[t] = 0.f; sqs[t] = 0.f; }

    #pragma unroll
    for (int st = 0; st < 2; ++st) {
        int r0 = blockIdx.x * 8 + st * 4;
        int n  = r0 / 300;
        int t0 = r0 - n * 300;          // 4 | 300 -> n uniform over the 4 rows
        const float* xwin = x0 + (size_t)n * 480000 + t0 * 25;

        build_afm(xwin, a_fm32, offs, mk, lane, w);
        __syncthreads();

        #pragma unroll
        for (int t = 0; t < 7; ++t) {
            bf16x8 a0 = afp[(t * 2 + 0) * 64 + lane];
            bf16x8 a1 = afp[(t * 2 + 1) * 64 + lane];
            f32x4 acc = {0.f, 0.f, 0.f, 0.f};
            acc = __builtin_amdgcn_mfma_f32_16x16x32_bf16(a0, bfrag0, acc, 0, 0, 0);
            acc = __builtin_amdgcn_mfma_f32_16x16x32_bf16(a1, bfrag1, acc, 0, 0, 0);
            #pragma unroll
            for (int r = 0; r < 4; ++r) {
                float y = acc[r] + breg;
                sums[t] += y;
                sqs[t]   = fmaf(y, y, sqs[t]);
            }
        }
        __syncthreads();   // a_fm reads done before next sub-tile rebuild
    }

    #pragma unroll
    for (int t = 0; t < 7; ++t) {
        int v = t * 4 + q;              // C-layout: row quad == v within tile
        if (v < V_) {
            atomicAdd(&ws[WS_SUM + v * 64 + d], sums[t]);
            atomicAdd(&ws[WS_SQ  + v * 64 + d], sqs[t]);
        }
    }
}

// ---------- pass 2: recompute y, shift_out, BN affine, residual, ReLU ----------
__global__ __launch_bounds__(256) void pass2_out(
    const float* __restrict__ x0, const float* __restrict__ bg,
    const float* __restrict__ ws, float* __restrict__ out)
{
    // a_fm 14336 B + y_lds 25600 B = 39936 B -> 4 blocks/CU
    __shared__ __align__(16) unsigned int a_fm32[3584];
    __shared__ __align__(16) float y_lds[6400];   // [d][dt*25 + v]
    const bf16x8* afp = (const bf16x8*)a_fm32;

    int tid = threadIdx.x;
    int lane = tid & 63, w = tid >> 6;
    int l15 = lane & 15, q = lane >> 4;
    int d = w * 16 + l15;

    const unsigned short* Wbf = (const unsigned short*)(ws + WS_WBF);
    bf16x8 bfrag0, bfrag1;
    #pragma unroll
    for (int j = 0; j < 8; ++j) {
        bfrag0[j] = (short)Wbf[(q * 8 + j) * 64 + d];
        bfrag1[j] = (short)Wbf[(32 + q * 8 + j) * 64 + d];
    }
    float breg = bg[d];

    int r0 = blockIdx.x * 4;
    int n  = r0 / 300;
    int t0 = r0 - n * 300;
    const float* xwin = x0 + (size_t)n * 480000 + t0 * 25;

    build_afm(xwin, a_fm32, (const int*)ws + WS_OFF, ws + WS_MK, lane, w);
    __syncthreads();

    #pragma unroll
    for (int t = 0; t < 7; ++t) {
        bf16x8 a0 = afp[(t * 2 + 0) * 64 + lane];
        bf16x8 a1 = afp[(t * 2 + 1) * 64 + lane];
        f32x4 acc = {0.f, 0.f, 0.f, 0.f};
        acc = __builtin_amdgcn_mfma_f32_16x16x32_bf16(a0, bfrag0, acc, 0, 0, 0);
        acc = __builtin_amdgcn_mfma_f32_16x16x32_bf16(a1, bfrag1, acc, 0, 0, 0);
        int v = t * 4 + q;
        if (v < V_) {
            // write y[v, dt=r, d]; bank = (4*l15 + r*25 + ...) -> exact 2-way: free
            #pragma unroll
            for (int r = 0; r < 4; ++r)
                y_lds[d * 100 + r * 25 + v] = acc[r] + breg;
        }
    }
    __syncthreads();

    const float* scp = ws + WS_SCALE;
    const float* shp = ws + WS_SHIFT;
    const int*   vpp = (const int*)ws + WS_VP;
    #pragma unroll
    for (int i = 0; i < 25; ++i) {        // 25*256 = 6400 outputs
        int e   = i * 256 + tid;
        int dd  = e / 100;
        int rem = e - dd * 100;
        int dt  = rem / 25;
        int v   = rem - dt * 25;
        int kk  = dd * 25 + v;            // tables in output order: coalesced
        int jj  = vpp[kk];
        float z = y_lds[(jj & 63) * 100 + dt * 25 + (jj >> 6)];
        int ga  = (n * 64 + dd) * 7500 + (t0 + dt) * 25 + v;
        float val = fmaf(z, scp[kk], shp[kk]) + x0[ga];
        __builtin_nontemporal_store(fmaxf(val, 0.f), &out[ga]);
    }
}

extern "C" void kernel_launch(void* const* d_in, const int* in_sizes, int n_in,
                              void* d_out, int out_size, void* d_ws, size_t ws_size,
                              hipStream_t stream)
{
    const float* x0    = (const float*)d_in[0];
    const float* fm    = (const float*)d_in[1];
    const float* W     = (const float*)d_in[2];
    const float* b     = (const float*)d_in[3];
    const float* gamma = (const float*)d_in[4];
    const float* beta  = (const float*)d_in[5];
    const int*   s_in  = (const int*)d_in[6];
    const int*   s_out = (const int*)d_in[7];
    float* out = (float*)d_out;
    float* ws  = (float*)d_ws;

    (void)hipMemsetAsync(ws + WS_SUM, 0, 2 * K_ * sizeof(float), stream);
    prep_tables<<<16, 256, 0, stream>>>(fm, W, s_in, ws);
    pass1_stats<<<R_ / 8, 256, 0, stream>>>(x0, b, ws);
    prep_scale_kernel<<<7, 256, 0, stream>>>(gamma, beta, s_out, ws);
    pass2_out<<<R_ / 4, 256, 0, stream>>>(x0, b, ws, out);
}

// Round 4
// 316.258 us; speedup vs baseline: 3.1061x; 1.0880x over previous
//
#include <hip/hip_runtime.h>
#include <math.h>

// Problem constants
#define V_ 25
#define C_ 64
#define D_ 64
#define N_ 64
#define T_ 300
#define R_ (N_*T_)      // 19200 rows
#define K_ (V_*C_)      // 1600
#define BN_EPS 1e-5f

// Workspace layout (4-byte units)
#define WS_GM     0      // (bf16(mask)<<16) | lds_off, k order     [1600] u32
#define WS_SCALE  1600   // BN scale, OUTPUT order kk=dd*25+v       [1600] f32
#define WS_SHIFT  3200   // BN shift, OUTPUT order kk               [1600] f32
#define WS_VP     4800   // s_out jj, OUTPUT order kk               [1600] i32
#define WS_SUM    6400   // sum_y per (v,d) flat jj                 [1600] f32
#define WS_SQ     8000   // sumsq_y per (v,d) flat jj               [1600] f32
#define WS_WBF    9600   // W as bf16                               [4096] u16

using bf16x8 = __attribute__((ext_vector_type(8))) short;
using f32x4  = __attribute__((ext_vector_type(4))) float;

__device__ __forceinline__ unsigned short f2bf(float f) {
    unsigned u = __float_as_uint(f);
    return (unsigned short)((u + 0x7FFFu + ((u >> 16) & 1u)) >> 16);
}

// ---------- prep: combined mask/offset table (k order) + bf16 W ----------
__global__ __launch_bounds__(256) void prep_tables(
    const float* __restrict__ fm, const float* __restrict__ W,
    const int* __restrict__ s_in, float* __restrict__ ws)
{
    int idx = blockIdx.x * 256 + threadIdx.x;   // 16 blocks -> 4096
    if (idx < K_) {
        int jj  = s_in[idx];
        int off = (jj & 63) * 100 + (jj >> 6);          // LDS offset, fits 16 bits
        unsigned mk = (unsigned)f2bf(tanhf(fm[idx]) + 1.0f);
        ((unsigned*)ws)[WS_GM + idx] = (mk << 16) | (unsigned)off;
    }
    if (idx < C_ * D_) ((unsigned short*)(ws + WS_WBF))[idx] = f2bf(W[idx]);
}

// ---------- prep: BN scale/shift + shift_out table, OUTPUT order ----------
__global__ __launch_bounds__(256) void prep_scale_kernel(
    const float* __restrict__ gamma, const float* __restrict__ beta,
    const int* __restrict__ s_out, float* __restrict__ ws)
{
    int kk = blockIdx.x * 256 + threadIdx.x;    // kk = dd*25 + v
    if (kk < K_) {
        int dd = kk / 25;
        int v  = kk - dd * 25;
        int k  = v * 64 + dd;
        int jj = s_out[k];
        float mean = ws[WS_SUM + jj] * (1.0f / (float)R_);
        float var  = fmaf(-mean, mean, ws[WS_SQ + jj] * (1.0f / (float)R_));
        float inv  = rsqrtf(var + BN_EPS);
        float sc   = gamma[k] * inv;
        ws[WS_SCALE + kk] = sc;
        ws[WS_SHIFT + kk] = beta[k] - mean * sc;
        ((int*)ws)[WS_VP + kk] = jj;
    }
}

// Stage the 4-row window into LDS with coalesced float4 loads.
// xs[c*100 + dt*25 + v] = x0[n, c, t0+dt, v]. 1600 float4 total.
__device__ __forceinline__ void stage_xs(
    const float* __restrict__ xwin, float4* xs4, int tid)
{
    const float4* s4 = (const float4*)xwin;     // t0 % 4 == 0 -> 16B aligned
    #pragma unroll
    for (int i = 0; i < 7; ++i) {
        int idx = i * 256 + tid;
        if (idx < 1600) {
            int c = idx / 25;
            int r = idx - c * 25;
            xs4[c * 25 + r] = s4[c * 1875 + r];
        }
    }
}

// Preload this thread's 28 gather-table entries (same for every window).
__device__ __forceinline__ void load_gmr(
    const unsigned* __restrict__ gmt, unsigned gmr[28], int lane, int w)
{
    int jw = lane & 3;
    int vh = lane >> 4;             // m>>2 where m=lane>>2
    #pragma unroll
    for (int i = 0; i < 14; ++i) {
        int combo = i * 4 + w;      // (T,q2)
        int T  = combo >> 2;
        int q2 = combo & 3;
        int t  = T >> 1;
        int c0 = (T & 1) * 32 + q2 * 8 + jw * 2;
        int v  = t * 4 + vh;
        int kb = (v < V_) ? (v * 64 + c0) : c0;   // clamp padded rows
        gmr[2 * i]     = gmt[kb];
        gmr[2 * i + 1] = gmt[kb + 1];
    }
}

// Build fragment-major bf16 A buffer from staged xs. Same a_fm layout/semantics
// as R3 (verified): word (T*64+q2*16+m)*4+jw, bank == lane&31 on writes.
__device__ __forceinline__ void build_afm(
    const float* xs, unsigned* a_fm32, const unsigned gmr[28], int lane, int w)
{
    int m  = lane >> 2;
    int jw = lane & 3;
    int dt = m & 3;
    #pragma unroll
    for (int i = 0; i < 14; ++i) {
        int combo = i * 4 + w;
        int T  = combo >> 2;
        int q2 = combo & 3;
        unsigned g0 = gmr[2 * i], g1 = gmr[2 * i + 1];
        float m0 = __uint_as_float(g0 & 0xFFFF0000u);
        float m1 = __uint_as_float(g1 & 0xFFFF0000u);
        float f0 = xs[(g0 & 0xFFFFu) + dt * 25] * m0;
        float f1 = xs[(g1 & 0xFFFFu) + dt * 25] * m1;
        a_fm32[(T * 64 + q2 * 16 + m) * 4 + jw] =
            (unsigned)f2bf(f0) | ((unsigned)f2bf(f1) << 16);
    }
}

// ---------- pass 1: BN statistics (16 rows = 4 windows per block) ----------
__global__ __launch_bounds__(256, 4) void pass1_stats(
    const float* __restrict__ x0, const float* __restrict__ bg,
    float* __restrict__ ws)
{
    __shared__ __align__(16) float4 xs4[1600];            // 25600 B
    __shared__ __align__(16) unsigned a_fm32[3584];       // 14336 B
    const float* xs = (const float*)xs4;
    const bf16x8* afp = (const bf16x8*)a_fm32;

    int tid = threadIdx.x;
    int lane = tid & 63, w = tid >> 6;
    int l15 = lane & 15, q = lane >> 4;
    int d = w * 16 + l15;

    const unsigned short* Wbf = (const unsigned short*)(ws + WS_WBF);
    bf16x8 bfrag0, bfrag1;
    #pragma unroll
    for (int j = 0; j < 8; ++j) {
        bfrag0[j] = (short)Wbf[(q * 8 + j) * 64 + d];
        bfrag1[j] = (short)Wbf[(32 + q * 8 + j) * 64 + d];
    }
    float breg = bg[d];

    unsigned gmr[28];
    load_gmr((const unsigned*)ws + WS_GM, gmr, lane, w);

    float sums[7], sqs[7];
    #pragma unroll
    for (int t = 0; t < 7; ++t) { sums[t] = 0.f; sqs[t] = 0.f; }

    #pragma unroll 1
    for (int st = 0; st < 4; ++st) {
        int r0 = blockIdx.x * 16 + st * 4;
        int n  = r0 / 300;
        int t0 = r0 - n * 300;          // 4 | 300 -> n uniform over the 4 rows
        const float* xwin = x0 + (size_t)n * 480000 + t0 * 25;

        stage_xs(xwin, xs4, tid);
        __syncthreads();
        build_afm(xs, a_fm32, gmr, lane, w);
        __syncthreads();

        #pragma unroll
        for (int t = 0; t < 7; ++t) {
            bf16x8 a0 = afp[(t * 2 + 0) * 64 + lane];
            bf16x8 a1 = afp[(t * 2 + 1) * 64 + lane];
            f32x4 acc = {0.f, 0.f, 0.f, 0.f};
            acc = __builtin_amdgcn_mfma_f32_16x16x32_bf16(a0, bfrag0, acc, 0, 0, 0);
            acc = __builtin_amdgcn_mfma_f32_16x16x32_bf16(a1, bfrag1, acc, 0, 0, 0);
            #pragma unroll
            for (int r = 0; r < 4; ++r) {
                float y = acc[r] + breg;
                sums[t] += y;
                sqs[t]   = fmaf(y, y, sqs[t]);
            }
        }
        __syncthreads();   // a_fm + xs reads done before next window overwrites
    }

    #pragma unroll
    for (int t = 0; t < 7; ++t) {
        int v = t * 4 + q;              // C-layout: row quad == v within tile
        if (v < V_) {
            atomicAdd(&ws[WS_SUM + v * 64 + d], sums[t]);
            atomicAdd(&ws[WS_SQ  + v * 64 + d], sqs[t]);
        }
    }
}

// ---------- pass 2: recompute y, shift_out, BN affine, residual, ReLU ----------
__global__ __launch_bounds__(256, 4) void pass2_out(
    const float* __restrict__ x0, const float* __restrict__ bg,
    const float* __restrict__ ws, float* __restrict__ out)
{
    // xs (25600 B) and y_lds (25600 B) are time-disjoint -> union. +a_fm 14336.
    __shared__ __align__(16) char smem[25600 + 14336];    // 39936 B
    float4* xs4   = (float4*)smem;
    const float* xs = (const float*)smem;
    float* y_lds  = (float*)smem;                          // [d][dt*25 + v]
    unsigned* a_fm32 = (unsigned*)(smem + 25600);
    const bf16x8* afp = (const bf16x8*)a_fm32;

    int tid = threadIdx.x;
    int lane = tid & 63, w = tid >> 6;
    int l15 = lane & 15, q = lane >> 4;
    int d = w * 16 + l15;

    const unsigned short* Wbf = (const unsigned short*)(ws + WS_WBF);
    bf16x8 bfrag0, bfrag1;
    #pragma unroll
    for (int j = 0; j < 8; ++j) {
        bfrag0[j] = (short)Wbf[(q * 8 + j) * 64 + d];
        bfrag1[j] = (short)Wbf[(32 + q * 8 + j) * 64 + d];
    }
    float breg = bg[d];

    unsigned gmr[28];
    load_gmr((const unsigned*)ws + WS_GM, gmr, lane, w);

    int r0 = blockIdx.x * 4;
    int n  = r0 / 300;
    int t0 = r0 - n * 300;
    const float* xwin = x0 + (size_t)n * 480000 + t0 * 25;

    stage_xs(xwin, xs4, tid);
    __syncthreads();
    build_afm(xs, a_fm32, gmr, lane, w);
    __syncthreads();                    // xs dead from here; y_lds takes over

    #pragma unroll
    for (int t = 0; t < 7; ++t) {
        bf16x8 a0 = afp[(t * 2 + 0) * 64 + lane];
        bf16x8 a1 = afp[(t * 2 + 1) * 64 + lane];
        f32x4 acc = {0.f, 0.f, 0.f, 0.f};
        acc = __builtin_amdgcn_mfma_f32_16x16x32_bf16(a0, bfrag0, acc, 0, 0, 0);
        acc = __builtin_amdgcn_mfma_f32_16x16x32_bf16(a1, bfrag1, acc, 0, 0, 0);
        int v = t * 4 + q;
        if (v < V_) {
            // y[v, dt=r, d]: bank stride 4 per l15, exact 2-way across wave: free
            #pragma unroll
            for (int r = 0; r < 4; ++r)
                y_lds[d * 100 + r * 25 + v] = acc[r] + breg;
        }
    }
    __syncthreads();

    const float* scp = ws + WS_SCALE;
    const float* shp = ws + WS_SHIFT;
    const int*   vpp = (const int*)ws + WS_VP;
    #pragma unroll
    for (int i = 0; i < 25; ++i) {        // 25*256 = 6400 outputs
        int e   = i * 256 + tid;
        int dd  = e / 100;
        int rem = e - dd * 100;
        int dt  = rem / 25;
        int v   = rem - dt * 25;
        int kk  = dd * 25 + v;            // tables in output order: coalesced
        int jj  = vpp[kk];
        float z = y_lds[(jj & 63) * 100 + dt * 25 + (jj >> 6)];
        int ga  = (n * 64 + dd) * 7500 + (t0 + dt) * 25 + v;
        float val = fmaf(z, scp[kk], shp[kk]) + x0[ga];   // residual: L2-warm
        __builtin_nontemporal_store(fmaxf(val, 0.f), &out[ga]);
    }
}

extern "C" void kernel_launch(void* const* d_in, const int* in_sizes, int n_in,
                              void* d_out, int out_size, void* d_ws, size_t ws_size,
                              hipStream_t stream)
{
    const float* x0    = (const float*)d_in[0];
    const float* fm    = (const float*)d_in[1];
    const float* W     = (const float*)d_in[2];
    const float* b     = (const float*)d_in[3];
    const float* gamma = (const float*)d_in[4];
    const float* beta  = (const float*)d_in[5];
    const int*   s_in  = (const int*)d_in[6];
    const int*   s_out = (const int*)d_in[7];
    float* out = (float*)d_out;
    float* ws  = (float*)d_ws;

    (void)hipMemsetAsync(ws + WS_SUM, 0, 2 * K_ * sizeof(float), stream);
    prep_tables<<<16, 256, 0, stream>>>(fm, W, s_in, ws);
    pass1_stats<<<R_ / 16, 256, 0, stream>>>(x0, b, ws);
    prep_scale_kernel<<<7, 256, 0, stream>>>(gamma, beta, s_out, ws);
    pass2_out<<<R_ / 4, 256, 0, stream>>>(x0, b, ws, out);
}